// Round 4
// baseline (1794.909 us; speedup 1.0000x reference)
//
#include <hip/hip_runtime.h>
#include <math.h>

// LSTM: B=64, T=2048, I=200, H=100. Output h_T [64,100] fp32.
//   prep_kernel : Wt[k][g'] = W_ih[orig(g')][k], bias' = (b_ih+b_hh) permuted,
//                 where g' = 4q+s (interleaved gate order), padded to 512.
//   xproj_kernel: xg[b,t,g'] = x[b,t,:].Wt[:,g'] + bias'[g']  (fp32 GEMM, pk_fma)
//   lstm_kernel : 64 WGs (one per batch), 256 thr = 4 waves = 1 wave/SIMD,
//                 waves_per_eu(1,1) -> 512-VGPR budget. Lane 2p+sb owns orig gates
//                 (2sb)*100+p and (2sb+1)*100+p: 200 VGPRs of W_hh weights resident.
//                 Pair exchange via quad_perm [1,0,3,2]; double-buffered h in LDS;
//                 ONE barrier/step; xg read as one float2/lane, depth-2 prefetch.

#define T_TOTAL 2048
#define B_SZ 64
#define IN_SZ 200
#define H_SZ 100
#define GP 512  // padded gate dim (4*H=400 -> 512)

typedef float v2f __attribute__((ext_vector_type(2)));

__device__ __forceinline__ float sigf(float x) {
    return __builtin_amdgcn_rcpf(1.f + __expf(-x));
}

// swap within lane pairs: quad_perm [1,0,3,2] -> ctrl 0xB1
#define QSWAP(x) \
    __int_as_float(__builtin_amdgcn_mov_dpp(__float_as_int(x), 0xB1, 0xF, 0xF, true))

// ---------------- prep: permuted-transpose W_ih, combined bias ----------------
__global__ void prep_kernel(const float* __restrict__ W_ih,
                            const float* __restrict__ b_ih,
                            const float* __restrict__ b_hh,
                            float* __restrict__ Wt,
                            float* __restrict__ bias) {
    int idx = blockIdx.x * 256 + threadIdx.x;
    if (idx < IN_SZ * GP) {
        int k = idx >> 9;
        int gp = idx & (GP - 1);
        int q = gp >> 2, s = gp & 3;          // g' = 4q+s
        int orig = s * H_SZ + q;
        Wt[idx] = (gp < 400) ? W_ih[orig * IN_SZ + k] : 0.f;
    }
    if (idx < GP) {
        int q = idx >> 2, s = idx & 3;
        int orig = s * H_SZ + q;
        bias[idx] = (idx < 400) ? (b_ih[orig] + b_hh[orig]) : 0.f;
    }
}

// ---------------- input projection GEMM (pk_fma packed) ----------------
__global__ __launch_bounds__(256, 4) void xproj_kernel(
    const float* __restrict__ x, const float* __restrict__ Wt,
    const float* __restrict__ bias, float* __restrict__ xg,
    int t0, int Tlen) {
    __shared__ __align__(16) float xTc[50][68];
    __shared__ __align__(16) float4 LW[50][32];

    const int tid = threadIdx.x;
    const int gblk = blockIdx.x;
    const int tbase = t0 + blockIdx.y * 64;
    const int b = blockIdx.z;
    const int gt = tid & 15;
    const int tt = tid >> 4;

    v2f acc[4][4];
#pragma unroll
    for (int r = 0; r < 4; ++r)
#pragma unroll
        for (int h = 0; h < 4; ++h) { acc[r][h].x = 0.f; acc[r][h].y = 0.f; }

    const float2* x2 = (const float2*)x;
    const float4* Wt4 = (const float4*)Wt;

    for (int kc = 0; kc < 4; ++kc) {
        for (int idx = tid; idx < 64 * 25; idx += 256) {
            int row = idx / 25, c2 = idx % 25;
            float2 v = x2[(size_t)(b * T_TOTAL + tbase + row) * (IN_SZ / 2) + kc * 25 + c2];
            xTc[c2 * 2][row] = v.x;
            xTc[c2 * 2 + 1][row] = v.y;
        }
        for (int idx = tid; idx < 50 * 32; idx += 256) {
            int k = idx >> 5, c = idx & 31;
            LW[k][c] = Wt4[(size_t)(kc * 50 + k) * (GP / 4) + gblk * 32 + c];
        }
        __syncthreads();

#pragma unroll 5
        for (int k = 0; k < 50; ++k) {
            float4 xv = *(const float4*)&xTc[k][tt * 4];
            float4 w0 = LW[k][gt];
            float4 w1 = LW[k][16 + gt];
            v2f wv[4];
            wv[0].x = w0.x; wv[0].y = w0.y; wv[1].x = w0.z; wv[1].y = w0.w;
            wv[2].x = w1.x; wv[2].y = w1.y; wv[3].x = w1.z; wv[3].y = w1.w;
            float xa[4] = {xv.x, xv.y, xv.z, xv.w};
#pragma unroll
            for (int tr = 0; tr < 4; ++tr) {
                v2f xs; xs.x = xa[tr]; xs.y = xa[tr];
#pragma unroll
                for (int h = 0; h < 4; ++h)
                    acc[tr][h] = __builtin_elementwise_fma(xs, wv[h], acc[tr][h]);
            }
        }
        __syncthreads();
    }

    const float4* bias4 = (const float4*)bias;
    float4 b0 = bias4[gblk * 32 + gt];
    float4 b1 = bias4[gblk * 32 + 16 + gt];
    float4* o4 = (float4*)xg;
#pragma unroll
    for (int tr = 0; tr < 4; ++tr) {
        int trow = (tbase - t0) + tt * 4 + tr;
        size_t o = (size_t)(b * Tlen + trow) * (GP / 4) + gblk * 32;
        float4 v0 = make_float4(acc[tr][0].x + b0.x, acc[tr][0].y + b0.y,
                                acc[tr][1].x + b0.z, acc[tr][1].y + b0.w);
        float4 v1 = make_float4(acc[tr][2].x + b1.x, acc[tr][2].y + b1.y,
                                acc[tr][3].x + b1.z, acc[tr][3].y + b1.w);
        o4[o + gt] = v0;
        o4[o + 16 + gt] = v1;
    }
}

// ---------------- recurrence: one WG (256 thr = 4 waves = 1/SIMD) per batch ----------------
__global__ __attribute__((amdgpu_flat_work_group_size(256, 256), amdgpu_waves_per_eu(1, 1)))
void lstm_kernel(
    const float* __restrict__ xg, const float* __restrict__ Whh,
    float* __restrict__ hstate, float* __restrict__ cstate,
    float* __restrict__ out, int Tlen, int first, int last) {
    __shared__ __align__(16) float4 hsh4[2][25];  // double-buffered h[100]
    float* hshf = (float*)hsh4;

    const int b = blockIdx.x;
    const int tid = threadIdx.x;
    const int p = tid >> 1;        // pair = hidden index q
    const int sb = tid & 1;        // 0: gates i,f ; 1: gates g,o
    const int pc = (p < H_SZ) ? p : (H_SZ - 1);
    const bool store_lane = (tid < 200) && (sb == 0);

    // two W_hh rows per lane, resident in VGPRs (200 regs)
    const int r0 = (2 * sb) * H_SZ + pc;
    const int r1 = (2 * sb + 1) * H_SZ + pc;
    v2f w0[50], w1[50];
    {
        const v2f* W2 = (const v2f*)Whh;  // row = 50 v2f
#pragma unroll
        for (int m = 0; m < 50; ++m) w0[m] = W2[(size_t)r0 * 50 + m];
#pragma unroll
        for (int m = 0; m < 50; ++m) w1[m] = W2[(size_t)r1 * 50 + m];
    }

    // activation params: slot0 = gate i (sigmoid) on even, gate g (tanh) on odd
    const float s0scale = sb ? 2.f : 1.f;
    const float s0mul   = sb ? 2.f : 1.f;
    const float s0add   = sb ? -1.f : 0.f;

    float c = first ? 0.f : cstate[b * H_SZ + pc];
    if (tid < H_SZ) hshf[tid] = first ? 0.f : hstate[b * H_SZ + tid];
    __syncthreads();

    const v2f* xg2 = (const v2f*)xg;               // row stride = 256 v2f
    const size_t base = (size_t)b * Tlen * (GP / 2);

    // depth-2 prefetch; lanes 200..255 read zero-pad (in-bounds, harmless)
    v2f xa = xg2[base + tid];
    v2f xb = xg2[base + (size_t)((1 < Tlen) ? 1 : 0) * (GP / 2) + tid];
    float hval = 0.f;

    for (int tl = 0; tl < Tlen; ++tl) {
        int tpre = tl + 2; if (tpre >= Tlen) tpre = Tlen - 1;
        v2f xn = xg2[base + (size_t)tpre * (GP / 2) + tid];

        const v2f* hb = (const v2f*)hsh4[tl & 1];
        v2f a0; a0.x = 0.f; a0.y = 0.f;
        v2f a1; a1.x = 0.f; a1.y = 0.f;
#pragma unroll
        for (int m = 0; m < 50; ++m) {
            v2f hv = hb[m];
            a0 = __builtin_elementwise_fma(hv, w0[m], a0);
            a1 = __builtin_elementwise_fma(hv, w1[m], a1);
        }
        float dot0 = xa.x + (a0.x + a0.y);
        float dot1 = xa.y + (a1.x + a1.y);

        float act0 = __builtin_fmaf(sigf(s0scale * dot0), s0mul, s0add);  // i or tanh g
        float act1 = sigf(dot1);                                          // f or o
        float e0 = QSWAP(act0);
        float e1 = QSWAP(act1);
        float vi = sb ? e0 : act0;
        float vf = sb ? e1 : act1;
        float vg = sb ? act0 : e0;
        float vo = sb ? act1 : e1;
        c = __builtin_fmaf(vf, c, vi * vg);
        float tc = __builtin_fmaf(sigf(2.f * c), 2.f, -1.f);  // tanh(c)
        hval = vo * tc;
        if (store_lane) hshf[((tl & 1) ^ 1) * H_SZ + p] = hval;
        __syncthreads();
        xa = xb; xb = xn;
    }

    if (store_lane) {
        hstate[b * H_SZ + p] = hval;
        cstate[b * H_SZ + p] = c;
        if (last) out[b * H_SZ + p] = hval;
    }
}

// ---------------- host ----------------
extern "C" void kernel_launch(void* const* d_in, const int* in_sizes, int n_in,
                              void* d_out, int out_size, void* d_ws, size_t ws_size,
                              hipStream_t stream) {
    const float* x    = (const float*)d_in[0];
    const float* W_ih = (const float*)d_in[1];
    const float* W_hh = (const float*)d_in[2];
    const float* b_ih = (const float*)d_in[3];
    const float* b_hh = (const float*)d_in[4];
    float* out = (float*)d_out;

    char* ws = (char*)d_ws;
    float* Wt     = (float*)(ws);
    float* bias   = (float*)(ws + 409600);
    float* hstate = (float*)(ws + 411648);
    float* cstate = (float*)(ws + 437248);
    float* xgbuf  = (float*)(ws + 462848);

    size_t cap = (ws_size > 462848) ? (ws_size - 462848) : 0;
    long long tcmax = (long long)(cap / ((size_t)B_SZ * GP * 4));
    int Tc = (int)((tcmax / 64) * 64);
    if (Tc > T_TOTAL) Tc = T_TOTAL;
    if (Tc < 64) Tc = 64;

    prep_kernel<<<400, 256, 0, stream>>>(W_ih, b_ih, b_hh, Wt, bias);

    for (int t0 = 0; t0 < T_TOTAL; t0 += Tc) {
        int Tlen = T_TOTAL - t0;
        if (Tlen > Tc) Tlen = Tc;
        xproj_kernel<<<dim3(4, Tlen / 64, B_SZ), 256, 0, stream>>>(x, Wt, bias, xgbuf, t0, Tlen);
        lstm_kernel<<<B_SZ, 256, 0, stream>>>(xgbuf, W_hh, hstate, cstate, out,
                                              Tlen, t0 == 0 ? 1 : 0,
                                              (t0 + Tlen) == T_TOTAL ? 1 : 0);
    }
}